// Round 10
// baseline (61.214 us; speedup 1.0000x reference)
//
#include <hip/hip_runtime.h>
#include <hip/hip_bf16.h>
#include <stdint.h>

// Embedding TTM order-4:
//   O1[p=225][m=64][c=64]  = sum_{r1<32} U0[0,i0,o0,r1] * U1[r1,i1,o1,c]   (p=i0*15+i1, m=o0*8+o1)
//   O2t[q=225][d=64][c=64] = sum_{r3<32} U2[c,i2,o2,r3] * U3[r3,i3,o3,0]   (q=i2*15+i3, d=o2*8+o3)
//   per element e: row0=x[e]/225, row1=x[e]%225
//   out[e][m][d] = sum_c O1[row0][m][c] * O2t[row1][d][c]
//
// Cache-policy experiment (vs r8): PLAIN stores (L2 write-back aggregation,
// fill-kernel path) + NONTEMPORAL table loads (no L2 allocate -> table lines
// can't be evicted by the write stream; reads served from L3, 3.7MB resident).

typedef __attribute__((ext_vector_type(8))) __bf16 bf16x8;
typedef __attribute__((ext_vector_type(4))) float f32x4;

__device__ inline unsigned short f2bf(float f) {
    union { float f; unsigned u; } v; v.f = f;
    unsigned u = v.u;
    return (unsigned short)((u + 0x7fffu + ((u >> 16) & 1u)) >> 16);  // RNE
}

// ---------------- build O1 and O2t in one launch (450 blocks, r8 verbatim) ----------------
__global__ __launch_bounds__(256) void build_tables(const float* __restrict__ U0,
                                                    const float* __restrict__ U1,
                                                    const float* __restrict__ U2,
                                                    const float* __restrict__ U3,
                                                    unsigned short* __restrict__ O1,
                                                    unsigned short* __restrict__ O2) {
    // union: 256 + max(8192 [O1 path], 128*68=8704 [O2 path]) = 8960 floats (35.8 KB)
    __shared__ float smem[8960];
    const int b = blockIdx.x;
    const int t = threadIdx.x;

    f32x4 acc[4];
#pragma unroll
    for (int k = 0; k < 4; ++k) acc[k] = (f32x4){0.f, 0.f, 0.f, 0.f};

    if (b < 225) {
        // ---- O1[p][m][c], p = b; item k = t + 256k -> m=item>>4, cq=item&15 ----
        float* su0 = smem;          // [o0][r1]       256 floats
        float* su1 = smem + 256;    // [r1h][o1][c]   8192 floats
        const int p = b;
        const int i0 = p / 15, i1 = p % 15;
        const int o0b = t >> 7;
        const int o1 = (t >> 4) & 7;
        const int cq = t & 15;

        su0[t] = U0[i0 * 256 + t];   // t = o0*32 + r1

        for (int h = 0; h < 2; ++h) {
            __syncthreads();
            for (int j = t; j < 8192; j += 256) {   // j = r1h*512 + o1*64 + c (coalesced)
                int r1h = j >> 9, rem = j & 511;
                su1[j] = U1[((h * 16 + r1h) * 15 + i1) * 512 + rem];
            }
            __syncthreads();
#pragma unroll
            for (int r = 0; r < 16; ++r) {
                f32x4 bvec = *(const f32x4*)(su1 + r * 512 + o1 * 64 + cq * 4);  // k-invariant
#pragma unroll
                for (int k = 0; k < 4; ++k)
                    acc[k] += su0[(o0b + 2 * k) * 32 + h * 16 + r] * bvec;        // broadcast
            }
        }
#pragma unroll
        for (int k = 0; k < 4; ++k) {
            int item = t + k * 256;
            ushort4 s = { f2bf(acc[k][0]), f2bf(acc[k][1]), f2bf(acc[k][2]), f2bf(acc[k][3]) };
            *(ushort4*)(O1 + p * 4096 + item * 4) = s;
        }
    } else {
        // ---- O2t[q][d][c], q = b - 225; item = t_lo + 16k + 64*t_hi ----
        float* su3 = smem;          // [r3][o3]                     256 floats
        float* su2 = smem + 256;    // [o2*16+r3h][c], stride 68    8704 floats
        const int q = b - 225;
        const int i2 = q / 15, i3 = q % 15;
        const int t_lo = t & 15, t_hi = t >> 4;
        const int o2 = t_hi >> 1;
        const int o3b = (t_hi & 1) * 4;

        {
            int r3 = t >> 3, o3 = t & 7;
            su3[t] = U3[(r3 * 15 + i3) * 8 + o3];
        }

        for (int h = 0; h < 2; ++h) {
            __syncthreads();
            for (int j = t; j < 8192; j += 256) {   // j = c*128 + o2*16 + r3h
                int c = j >> 7, o2s = (j >> 4) & 7, r3h = j & 15;
                su2[(o2s * 16 + r3h) * 68 + c] =
                    U2[((c * 15 + i2) * 8 + o2s) * 32 + h * 16 + r3h];
            }
            __syncthreads();
#pragma unroll
            for (int r = 0; r < 16; ++r) {
                f32x4 bvec = *(const f32x4*)(su2 + (o2 * 16 + r) * 68 + t_lo * 4);  // k-invariant
#pragma unroll
                for (int k = 0; k < 4; ++k)
                    acc[k] += su3[(h * 16 + r) * 8 + o3b + k] * bvec;               // broadcast
            }
        }
#pragma unroll
        for (int k = 0; k < 4; ++k) {
            int item = t_lo + k * 16 + t_hi * 64;   // = d*16 + cq
            ushort4 s = { f2bf(acc[k][0]), f2bf(acc[k][1]), f2bf(acc[k][2]), f2bf(acc[k][3]) };
            *(ushort4*)(O2 + q * 4096 + item * 4) = s;   // [q][d][c]
        }
    }
}

// ---------------- main: one element per wave, 4 per block ----------------
__global__ __launch_bounds__(256) void ttm_main(const int* __restrict__ x,
                                                const unsigned short* __restrict__ O1,
                                                const unsigned short* __restrict__ O2,
                                                float* __restrict__ out, int ne) {
    // per-wave private staging tile: 16 rows x 68 dwords (stride-68 pad)
    __shared__ float lbuf[4][16 * 68];   // 17.4 KB/block, no barriers needed
    const int w = threadIdx.x >> 6;
    const int l = threadIdx.x & 63;
    const int e = blockIdx.x * 4 + w;
    if (e >= ne) return;

    const unsigned v = (unsigned)x[e];
    const unsigned row0 = v / 225u;
    const unsigned row1 = v - row0 * 225u;

    const int lr = l & 15;   // fragment row/col index
    const int lk = l >> 4;   // k-chunk group

    const unsigned short* Yp = O1 + (size_t)row0 * 4096;  // B-role: Y[c][m] from [m][c]
    const unsigned short* Xp = O2 + (size_t)row1 * 4096;  // A-role: X[d][c]

    bf16x8 Y[4][2], X[4][2];
#pragma unroll
    for (int mq = 0; mq < 4; ++mq)
#pragma unroll
        for (int h = 0; h < 2; ++h)
            Y[mq][h] = __builtin_nontemporal_load(
                (const bf16x8*)(Yp + (16 * mq + lr) * 64 + h * 32 + lk * 8));
#pragma unroll
    for (int nq = 0; nq < 4; ++nq)
#pragma unroll
        for (int h = 0; h < 2; ++h)
            X[nq][h] = __builtin_nontemporal_load(
                (const bf16x8*)(Xp + (16 * nq + lr) * 64 + h * 32 + lk * 8));

    float* Oe = out + (size_t)e * 4096;
    float* Lw = lbuf[w];

#pragma unroll
    for (int mq = 0; mq < 4; ++mq) {
        f32x4 acc[4];
#pragma unroll
        for (int nq = 0; nq < 4; ++nq) {
            acc[nq] = __builtin_amdgcn_mfma_f32_16x16x32_bf16(
                X[nq][0], Y[mq][0], (f32x4){0.f, 0.f, 0.f, 0.f}, 0, 0, 0);
            acc[nq] = __builtin_amdgcn_mfma_f32_16x16x32_bf16(
                X[nq][1], Y[mq][1], acc[nq], 0, 0, 0);
        }
        // stage this wave's 4KB chunk (rows 16mq..16mq+15) into LDS:
        // D[d= lk*4+reg][m-row = lr] -> L[lr][16nq + lk*4 .. +3]
#pragma unroll
        for (int nq = 0; nq < 4; ++nq)
            *(f32x4*)(Lw + lr * 68 + 16 * nq + 4 * lk) = acc[nq];

        // read back linearly, store fully coalesced (1KB contiguous per instr)
#pragma unroll
        for (int i = 0; i < 4; ++i) {
            int chunk = i * 64 + l;               // 0..255: 16B chunks of the 4KB
            int row = chunk >> 4, colq = chunk & 15;
            f32x4 vv = *(const f32x4*)(Lw + row * 68 + colq * 4);
            *(f32x4*)(Oe + 1024 * mq + chunk * 4) = vv;   // PLAIN store (L2 write-back)
        }
    }
}

extern "C" void kernel_launch(void* const* d_in, const int* in_sizes, int n_in,
                              void* d_out, int out_size, void* d_ws, size_t ws_size,
                              hipStream_t stream) {
    const int* x = (const int*)d_in[0];           // int64 in reference -> int32 in harness
    const float* U0 = (const float*)d_in[1];
    const float* U1 = (const float*)d_in[2];
    const float* U2 = (const float*)d_in[3];
    const float* U3 = (const float*)d_in[4];

    unsigned short* O1 = (unsigned short*)d_ws;       // 225*4096*2 = 1.8432 MB
    unsigned short* O2 = O1 + 225 * 4096;             // 1.8432 MB

    const int ne = in_sizes[0];  // 8192 lookups

    build_tables<<<450, 256, 0, stream>>>(U0, U1, U2, U3, O1, O2);
    ttm_main<<<(ne + 3) / 4, 256, 0, stream>>>(x, O1, O2, (float*)d_out, ne);
}

// Round 11
// 40.947 us; speedup vs baseline: 1.4950x; 1.4950x over previous
//
#include <hip/hip_runtime.h>
#include <hip/hip_bf16.h>
#include <stdint.h>

// Embedding TTM order-4:
//   O1[p=225][m=64][c=64]  = sum_{r1<32} U0[0,i0,o0,r1] * U1[r1,i1,o1,c]   (p=i0*15+i1, m=o0*8+o1)
//   O2t[q=225][d=64][c=64] = sum_{r3<32} U2[c,i2,o2,r3] * U3[r3,i3,o3,0]   (q=i2*15+i3, d=o2*8+o3)
//   per element e: row0=x[e]/225, row1=x[e]%225
//   out[e][m][d] = sum_c O1[row0][m][c] * O2t[row1][d][c]
//
// ttm (r8-best, verbatim): swapped-operand 16x16x32 MFMA, per-wave LDS tile,
// 1KB-per-instruction coalesced NT stores, cached table loads.
// builds: 1024-thread blocks, 1 row each, all 450 co-resident (16 waves/block
// for latency hiding); per-thread exactly one f32x4 output item.

typedef __attribute__((ext_vector_type(8))) __bf16 bf16x8;
typedef __attribute__((ext_vector_type(4))) float f32x4;

__device__ inline unsigned short f2bf(float f) {
    union { float f; unsigned u; } v; v.f = f;
    unsigned u = v.u;
    return (unsigned short)((u + 0x7fffu + ((u >> 16) & 1u)) >> 16);  // RNE
}

// ---------------- build O1 and O2t: 450 blocks x 1024 threads ----------------
__global__ __launch_bounds__(1024) void build_tables(const float* __restrict__ U0,
                                                     const float* __restrict__ U1,
                                                     const float* __restrict__ U2,
                                                     const float* __restrict__ U3,
                                                     unsigned short* __restrict__ O1,
                                                     unsigned short* __restrict__ O2) {
    // union: 256 + max(8192 [O1], 128*68=8704 [O2]) = 8960 floats (35.8 KB)
    __shared__ float smem[8960];
    const int b = blockIdx.x;
    const int t = threadIdx.x;

    f32x4 acc = (f32x4){0.f, 0.f, 0.f, 0.f};

    if (b < 225) {
        // ---- O1[p][m][c], p = b; thread t -> m = t>>4, cq = t&15 ----
        float* su0 = smem;          // [o0][r1]       256 floats
        float* su1 = smem + 256;    // [r1h][o1][c]   8192 floats
        const int p = b;
        const int i0 = p / 15, i1 = p % 15;
        const int o0 = t >> 7;            // m>>3 = t>>7
        const int o1 = (t >> 4) & 7;
        const int cq = t & 15;

        if (t < 256) su0[t] = U0[i0 * 256 + t];   // t = o0*32 + r1

        for (int h = 0; h < 2; ++h) {
            __syncthreads();
            // stage 8192 floats: j = r1h*512 + o1*64 + c (coalesced)
#pragma unroll
            for (int i = 0; i < 8; ++i) {
                int j = t + i * 1024;
                int r1h = j >> 9, rem = j & 511;
                su1[j] = U1[((h * 16 + r1h) * 15 + i1) * 512 + rem];
            }
            __syncthreads();
#pragma unroll
            for (int r = 0; r < 16; ++r) {
                f32x4 bvec = *(const f32x4*)(su1 + r * 512 + o1 * 64 + cq * 4);
                acc += su0[o0 * 32 + h * 16 + r] * bvec;   // broadcast scalar
            }
        }
        ushort4 s = { f2bf(acc[0]), f2bf(acc[1]), f2bf(acc[2]), f2bf(acc[3]) };
        *(ushort4*)(O1 + p * 4096 + t * 4) = s;           // item offset = 4t
    } else {
        // ---- O2t[q][d][c], q = b - 225; thread t -> d = t>>4, cq = t&15 ----
        float* su3 = smem;          // [r3][o3]                     256 floats
        float* su2 = smem + 256;    // [o2*16+r3h][c], stride 68    8704 floats
        const int q = b - 225;
        const int i2 = q / 15, i3 = q % 15;
        const int o2 = t >> 7;            // d>>3
        const int o3 = (t >> 4) & 7;      // d&7
        const int cq = t & 15;

        if (t < 256) {                    // t = r3*8 + o3s
            int r3 = t >> 3, o3s = t & 7;
            su3[t] = U3[(r3 * 15 + i3) * 8 + o3s];
        }

        for (int h = 0; h < 2; ++h) {
            __syncthreads();
            // stage transposed: j = c*128 + o2s*16 + r3h
#pragma unroll
            for (int i = 0; i < 8; ++i) {
                int j = t + i * 1024;
                int c = j >> 7, o2s = (j >> 4) & 7, r3h = j & 15;
                su2[(o2s * 16 + r3h) * 68 + c] =
                    U2[((c * 15 + i2) * 8 + o2s) * 32 + h * 16 + r3h];
            }
            __syncthreads();
#pragma unroll
            for (int r = 0; r < 16; ++r) {
                f32x4 bvec = *(const f32x4*)(su2 + (o2 * 16 + r) * 68 + cq * 4);
                acc += su3[(h * 16 + r) * 8 + o3] * bvec;  // broadcast scalar
            }
        }
        ushort4 s = { f2bf(acc[0]), f2bf(acc[1]), f2bf(acc[2]), f2bf(acc[3]) };
        *(ushort4*)(O2 + q * 4096 + t * 4) = s;           // [q][d][c], offset = 4t
    }
}

// ---------------- main: one element per wave, 4 per block (r8 verbatim) ----------------
__global__ __launch_bounds__(256) void ttm_main(const int* __restrict__ x,
                                                const unsigned short* __restrict__ O1,
                                                const unsigned short* __restrict__ O2,
                                                float* __restrict__ out, int ne) {
    // per-wave private staging tile: 16 rows x 68 dwords (stride-68 pad)
    __shared__ float lbuf[4][16 * 68];   // 17.4 KB/block, no barriers needed
    const int w = threadIdx.x >> 6;
    const int l = threadIdx.x & 63;
    const int e = blockIdx.x * 4 + w;
    if (e >= ne) return;

    const unsigned v = (unsigned)x[e];
    const unsigned row0 = v / 225u;
    const unsigned row1 = v - row0 * 225u;

    const int lr = l & 15;   // fragment row/col index
    const int lk = l >> 4;   // k-chunk group

    const unsigned short* Yp = O1 + (size_t)row0 * 4096;  // B-role: Y[c][m] from [m][c]
    const unsigned short* Xp = O2 + (size_t)row1 * 4096;  // A-role: X[d][c]

    bf16x8 Y[4][2], X[4][2];
#pragma unroll
    for (int mq = 0; mq < 4; ++mq)
#pragma unroll
        for (int h = 0; h < 2; ++h)
            Y[mq][h] = *(const bf16x8*)(Yp + (16 * mq + lr) * 64 + h * 32 + lk * 8);
#pragma unroll
    for (int nq = 0; nq < 4; ++nq)
#pragma unroll
        for (int h = 0; h < 2; ++h)
            X[nq][h] = *(const bf16x8*)(Xp + (16 * nq + lr) * 64 + h * 32 + lk * 8);

    float* Oe = out + (size_t)e * 4096;
    float* Lw = lbuf[w];

#pragma unroll
    for (int mq = 0; mq < 4; ++mq) {
        f32x4 acc[4];
#pragma unroll
        for (int nq = 0; nq < 4; ++nq) {
            acc[nq] = __builtin_amdgcn_mfma_f32_16x16x32_bf16(
                X[nq][0], Y[mq][0], (f32x4){0.f, 0.f, 0.f, 0.f}, 0, 0, 0);
            acc[nq] = __builtin_amdgcn_mfma_f32_16x16x32_bf16(
                X[nq][1], Y[mq][1], acc[nq], 0, 0, 0);
        }
        // stage this wave's 4KB chunk (rows 16mq..16mq+15) into LDS:
        // D[d= lk*4+reg][m-row = lr] -> L[lr][16nq + lk*4 .. +3]
#pragma unroll
        for (int nq = 0; nq < 4; ++nq)
            *(f32x4*)(Lw + lr * 68 + 16 * nq + 4 * lk) = acc[nq];

        // read back linearly, store fully coalesced (1KB contiguous per instr)
#pragma unroll
        for (int i = 0; i < 4; ++i) {
            int chunk = i * 64 + l;               // 0..255: 16B chunks of the 4KB
            int row = chunk >> 4, colq = chunk & 15;
            f32x4 vv = *(const f32x4*)(Lw + row * 68 + colq * 4);
            __builtin_nontemporal_store(vv, (f32x4*)(Oe + 1024 * mq + chunk * 4));
        }
    }
}

extern "C" void kernel_launch(void* const* d_in, const int* in_sizes, int n_in,
                              void* d_out, int out_size, void* d_ws, size_t ws_size,
                              hipStream_t stream) {
    const int* x = (const int*)d_in[0];           // int64 in reference -> int32 in harness
    const float* U0 = (const float*)d_in[1];
    const float* U1 = (const float*)d_in[2];
    const float* U2 = (const float*)d_in[3];
    const float* U3 = (const float*)d_in[4];

    unsigned short* O1 = (unsigned short*)d_ws;       // 225*4096*2 = 1.8432 MB
    unsigned short* O2 = O1 + 225 * 4096;             // 1.8432 MB

    const int ne = in_sizes[0];  // 8192 lookups

    build_tables<<<450, 1024, 0, stream>>>(U0, U1, U2, U3, O1, O2);
    ttm_main<<<(ne + 3) / 4, 256, 0, stream>>>(x, O1, O2, (float*)d_out, ne);
}